// Round 1
// baseline (186.570 us; speedup 1.0000x reference)
//
#include <hip/hip_runtime.h>

// N-gram embedding mean: out[b,s,:] = mean_k emb_table[ngram_ids[word_idx[b,s], k], :]
// with row 0 = padding (zero). Sizes fixed by the reference.
#define NUM_WORDS 32768   // B*S = 16*2048
#define KMAX 24
#define EDIM 128

__global__ __launch_bounds__(256) void ngram_emb_kernel(
    const int* __restrict__ word_idx,      // [B*S]
    const int* __restrict__ ngram_ids,     // [V, K]
    const int* __restrict__ ngram_counts,  // [V]
    const float* __restrict__ emb_table,   // [NG, E]
    float* __restrict__ out)               // [B*S, E]
{
    // one wave (64 lanes) per word; lane handles float2 -> 64*8B = 512B = one row
    const int gtid = blockIdx.x * blockDim.x + threadIdx.x;
    const int word = gtid >> 6;            // wave index == word position
    const int lane = threadIdx.x & 63;
    if (word >= NUM_WORDS) return;

    const int w   = word_idx[word];                  // same for all 64 lanes (broadcast)
    const int cnt = ngram_counts[w];
    const int* ids = ngram_ids + (long)w * KMAX;

    // lane-parallel prefetch of the word's ngram ids; broadcast via shuffle
    int my_id = (lane < KMAX) ? ids[lane] : 0;

    float ax = 0.f, ay = 0.f;
    const long col = (long)(lane * 2);
    for (int k = 0; k < cnt; ++k) {
        const int row = __shfl(my_id, k);            // wave-uniform row id
        if (row != 0) {                              // padding_idx=0 -> zero row
            const float2 v = *(const float2*)(emb_table + (long)row * EDIM + col);
            ax += v.x;
            ay += v.y;
        }
    }
    const float inv = 1.0f / (float)cnt;
    float2 r; r.x = ax * inv; r.y = ay * inv;
    *(float2*)(out + (long)word * EDIM + col) = r;
}

extern "C" void kernel_launch(void* const* d_in, const int* in_sizes, int n_in,
                              void* d_out, int out_size, void* d_ws, size_t ws_size,
                              hipStream_t stream) {
    const int*   word_idx     = (const int*)d_in[0];
    const int*   ngram_ids    = (const int*)d_in[1];
    const int*   ngram_counts = (const int*)d_in[2];
    const float* emb_table    = (const float*)d_in[3];
    float*       out          = (float*)d_out;

    // 32768 words * 64 lanes / 256 threads-per-block = 8192 blocks
    const int threads = 256;
    const int blocks  = (NUM_WORDS * 64) / threads;
    ngram_emb_kernel<<<blocks, threads, 0, stream>>>(
        word_idx, ngram_ids, ngram_counts, emb_table, out);
}

// Round 3
// 169.062 us; speedup vs baseline: 1.1036x; 1.1036x over previous
//
#include <hip/hip_runtime.h>

// N-gram embedding mean on gfx950. One wave per word.
// - word id & all 24 ngram ids pinned scalar via readfirstlane (no shuffles,
//   no divergence hazards; R2's divergent ds_bpermute bug eliminated).
// - slots processed in static groups of 8 with a wave-uniform cnt skip;
//   within a group all 8 row loads issue before any accumulate -> 8 rows
//   (4KB) in flight per wave to hide gather latency.
// - padding slots point at row 0: loaded (L1-hit) but masked via fmaf.
#define NUM_WORDS 32768   // B*S = 16*2048
#define KMAX 24
#define GROUP 8

__global__ __launch_bounds__(256) void ngram_emb_kernel(
    const int* __restrict__ word_idx,      // [B*S]
    const int* __restrict__ ngram_ids,     // [V, K]
    const int* __restrict__ ngram_counts,  // [V]
    const float* __restrict__ emb_table,   // [NG, E]
    float* __restrict__ out)               // [B*S, E]
{
    const int gtid = blockIdx.x * blockDim.x + threadIdx.x;
    const int word = gtid >> 6;            // one wave per word
    const int lane = threadIdx.x & 63;     // float2 chunk within the 512B row

    // wave-uniform scalars (full wave active here — readfirstlane is safe)
    const int w   = __builtin_amdgcn_readfirstlane(word_idx[word]);
    const int cnt = ngram_counts[w];       // uniform (scalar base)
    const int* ids = ngram_ids + w * KMAX;

    int rr[KMAX];
#pragma unroll
    for (int k = 0; k < KMAX; ++k)
        rr[k] = __builtin_amdgcn_readfirstlane(ids[k]);

    const float2* tbl = (const float2*)emb_table;   // row stride = 64 float2
    float ax = 0.f, ay = 0.f;

#pragma unroll
    for (int g = 0; g < KMAX; g += GROUP) {
        if (g < cnt) {                      // uniform branch: skip empty groups
            float2 v[GROUP];
            float  m[GROUP];
#pragma unroll
            for (int j = 0; j < GROUP; ++j) {
                const int r = rr[g + j];    // scalar row id (0 = padding)
                m[j] = r ? 1.f : 0.f;
                v[j] = tbl[(long)r * 64 + lane];   // unconditional; row 0 is L1-hot
            }
#pragma unroll
            for (int j = 0; j < GROUP; ++j) {
                ax = fmaf(m[j], v[j].x, ax);
                ay = fmaf(m[j], v[j].y, ay);
            }
        }
    }

    const float inv = 1.0f / (float)cnt;
    float2 o; o.x = ax * inv; o.y = ay * inv;
    ((float2*)out)[(long)word * 64 + lane] = o;    // 64 lanes x 8B = 512B row
}

extern "C" void kernel_launch(void* const* d_in, const int* in_sizes, int n_in,
                              void* d_out, int out_size, void* d_ws, size_t ws_size,
                              hipStream_t stream) {
    const int*   word_idx     = (const int*)d_in[0];
    const int*   ngram_ids    = (const int*)d_in[1];
    const int*   ngram_counts = (const int*)d_in[2];
    const float* emb_table    = (const float*)d_in[3];
    float*       out          = (float*)d_out;

    const int threads = 256;
    const int blocks  = (NUM_WORDS * 64) / threads;  // 8192
    ngram_emb_kernel<<<blocks, threads, 0, stream>>>(
        word_idx, ngram_ids, ngram_counts, emb_table, out);
}